// Round 10
// baseline (577.256 us; speedup 1.0000x reference)
//
#include <hip/hip_runtime.h>
#include <math.h>

#define ROW_N 2048
#define KSEL 10
#define WCAP 64   // fallback candidate cap

typedef float f32x4 __attribute__((ext_vector_type(4)));
typedef unsigned long long u64;

__device__ __forceinline__ uint32_t ordbits(float x) {
    uint32_t u = __float_as_uint(x);
    return u ^ ((uint32_t)((int32_t)u >> 31) | 0x80000000u);
}
__device__ __forceinline__ float unord(uint32_t o) {
    return __uint_as_float(o ^ ((o & 0x80000000u) ? 0x80000000u : 0xFFFFFFFFu));
}

// FOUR rows per wave, all loads issued up-front and PINNED in registers.
// r2-r9 plateau diagnosis: every pipe <40% => the bound is memory-level
// parallelism (burst 16 loads, then long loadless compute => ~2.5 TB/s by
// Little's law; r5's spill storm proved 4.65 TB/s mixed R/W is achievable
// on this shape). Fix: 32 dwordx4 loads in flight per wave, pair 1 flights
// under pair 0's whole compute. asm "+v" pins stop LLVM from sinking the
// prefetch or remat-reloading V in later phases (VGPR=36 in r8 = remat).
// Deliberate trade: VGPR ~160 -> 3 waves/SIMD; in-flight bytes, not wave
// count, set BW (fills hit 6.5 TB/s at 10% occupancy).
//
// Per pair (rows interleaved to overlap serial chains): one sweep gives
// per-lane top-3 + unshifted mass; 10th-largest VALUE bits via 16x 2-bit
// ballot search (3 independent trials/step => half the round-trips of 1-bit);
// fast path valid iff cnt(pool>=kov)==10 and no lane's 3rd elem >= kf ->
// winners are exactly {x>=kf}; else exact u64-key fallback (lax.top_k
// index tie-break). Output e*(sel?aa:bb), nontemporal, no patch pass.
__global__ __launch_bounds__(256) void topk_softmax_kernel(
    const float* __restrict__ in, float* __restrict__ out)
{
    const int lane = threadIdx.x & 63;
    const int wave = threadIdx.x >> 6;
    const size_t row0 = ((size_t)blockIdx.x * 4 + wave) * 4;

    __shared__ u64 s_cand[4][WCAP];   // fallback only, wave-private

    const float K = 1.4426950408889634f;
    const int low0 = 2047 - lane * 4;

    // all 4 rows: 32 outstanding dwordx4 loads per wave, pinned on arrival
    f32x4 V[4][8];
    #pragma unroll
    for (int p = 0; p < 4; ++p) {
        const f32x4* src = reinterpret_cast<const f32x4*>(in + (row0 + p) * ROW_N);
        #pragma unroll
        for (int j = 0; j < 8; ++j) {
            V[p][j] = src[j * 64 + lane];
            asm volatile("" : "+v"(V[p][j][0]), "+v"(V[p][j][1]),
                              "+v"(V[p][j][2]), "+v"(V[p][j][3]));
        }
    }

    auto emitRow = [&](f32x4 (&Vr)[8], size_t base, float kf, float c0v,
                       float tot, float ssum, bool fast) {
        f32x4* o4 = reinterpret_cast<f32x4*>(out + base);
        if (fast) {
            const float aa = 0.9f / ssum;
            const float bb = 0.1f / (tot - ssum);
            #pragma unroll
            for (int j = 0; j < 8; ++j) {
                f32x4 o;
                #pragma unroll
                for (int c = 0; c < 4; ++c) {
                    float x = Vr[j][c];
                    o[c] = exp2f(fmaf(x, K, c0v)) * ((x >= kf) ? aa : bb);
                }
                __builtin_nontemporal_store(o, o4 + j * 64 + lane);
            }
        } else {
            // exact fallback (~3% of rows): keys ov<<16|(2047-idx)
            int C = 0;
            #pragma unroll
            for (int j = 0; j < 8; ++j)
                #pragma unroll
                for (int c = 0; c < 4; ++c) {
                    bool cond = Vr[j][c] >= kf;
                    u64 m = __ballot(cond);
                    if (cond) {
                        uint32_t ov = ordbits(Vr[j][c]);
                        int pos = C + (int)__builtin_amdgcn_mbcnt_hi(
                                          (unsigned)(m >> 32),
                                          __builtin_amdgcn_mbcnt_lo((unsigned)m, 0u));
                        if (pos < WCAP)
                            s_cand[wave][pos] =
                                ((u64)ov << 16) | (unsigned)(low0 - (j * 256 + c));
                    }
                    C += __popcll(m);
                }
            if (C > WCAP) C = WCAP;
            u64 k0 = (lane < C) ? s_cand[wave][lane] : 0ULL;
            u64 kmin = 0ULL;
            #pragma unroll 1
            for (int b = 47; b >= 0; --b) {
                u64 trial = kmin | (1ULL << b);
                if (__popcll(__ballot(k0 >= trial)) >= KSEL) kmin = trial;
            }
            uint32_t ovk  = (uint32_t)(k0 >> 16);
            float val = unord(ovk);
            bool win  = (k0 >= kmin) && (k0 != 0ULL);
            float ee  = win ? exp2f(fmaf(val, K, c0v)) : 0.f;
            float ss = ee;
            #pragma unroll
            for (int off = 32; off > 0; off >>= 1) ss += __shfl_xor(ss, off);
            const float aa = 0.9f / ss;
            const float bb = 0.1f / (tot - ss);
            #pragma unroll
            for (int j = 0; j < 8; ++j) {
                f32x4 o;
                #pragma unroll
                for (int c = 0; c < 4; ++c) {
                    float x = Vr[j][c];
                    u64 key = ((u64)ordbits(x) << 16) |
                              (unsigned)(low0 - (j * 256 + c));
                    o[c] = exp2f(fmaf(x, K, c0v)) * ((key >= kmin) ? aa : bb);
                }
                __builtin_nontemporal_store(o, o4 + j * 64 + lane);
            }
        }
    };

    auto processPair = [&](f32x4 (&VA)[8], f32x4 (&VB)[8],
                           size_t baseA, size_t baseB) {
        float a1 = -INFINITY, a2 = -INFINITY, a3 = -INFINITY, tA0 = 0.f;
        float b1 = -INFINITY, b2 = -INFINITY, b3 = -INFINITY, tB0 = 0.f;
        #pragma unroll
        for (int j = 0; j < 8; ++j)
            #pragma unroll
            for (int c = 0; c < 4; ++c) {
                float xA = VA[j][c];
                a3 = fmaxf(fminf(xA, a2), a3);
                a2 = fmaxf(fminf(xA, a1), a2);
                a1 = fmaxf(xA, a1);
                tA0 += exp2f(xA * K);           // x bounded ~6: no overflow
                float xB = VB[j][c];
                b3 = fmaxf(fminf(xB, b2), b3);
                b2 = fmaxf(fminf(xB, b1), b2);
                b1 = fmaxf(xB, b1);
                tB0 += exp2f(xB * K);
            }

        float vmA = a1, vmB = b1;
        #pragma unroll
        for (int off = 32; off > 0; off >>= 1) {
            vmA = fmaxf(vmA, __shfl_xor(vmA, off)); tA0 += __shfl_xor(tA0, off);
            vmB = fmaxf(vmB, __shfl_xor(vmB, off)); tB0 += __shfl_xor(tB0, off);
        }

        const uint32_t oa1 = ordbits(a1), oa2 = ordbits(a2);
        const uint32_t ob1 = ordbits(b1), ob2 = ordbits(b2);
        auto cntA = [&](uint32_t t) {
            return __popcll(__ballot(oa1 >= t)) + __popcll(__ballot(oa2 >= t));
        };
        auto cntB = [&](uint32_t t) {
            return __popcll(__ballot(ob1 >= t)) + __popcll(__ballot(ob2 >= t));
        };

        // 2 bits per step: 3 independent trials share one ballot round-trip
        uint32_t kA = 0, kB = 0;
        #pragma unroll
        for (int b = 30; b >= 0; b -= 2) {
            uint32_t A3 = kA | (3u << b), A2 = kA | (2u << b), A1 = kA | (1u << b);
            uint32_t B3 = kB | (3u << b), B2 = kB | (2u << b), B1 = kB | (1u << b);
            int cA3 = cntA(A3), cA2 = cntA(A2), cA1 = cntA(A1);
            int cB3 = cntB(B3), cB2 = cntB(B2), cB1 = cntB(B1);
            kA = (cA3 >= KSEL) ? A3 : (cA2 >= KSEL) ? A2 : (cA1 >= KSEL) ? A1 : kA;
            kB = (cB3 >= KSEL) ? B3 : (cB2 >= KSEL) ? B2 : (cB1 >= KSEL) ? B1 : kB;
        }
        const float kfA = unord(kA), kfB = unord(kB);

        const bool fastA = (cntA(kA) == KSEL) && (__ballot(a3 >= kfA) == 0ULL);
        const bool fastB = (cntB(kB) == KSEL) && (__ballot(b3 >= kfB) == 0ULL);

        const float c0A = -vmA * K, c0B = -vmB * K;
        const float totA = tA0 * exp2f(c0A);
        const float totB = tB0 * exp2f(c0B);

        float eA = ((a1 >= kfA) ? exp2f(fmaf(a1, K, c0A)) : 0.f) +
                   ((a2 >= kfA) ? exp2f(fmaf(a2, K, c0A)) : 0.f);
        float eB = ((b1 >= kfB) ? exp2f(fmaf(b1, K, c0B)) : 0.f) +
                   ((b2 >= kfB) ? exp2f(fmaf(b2, K, c0B)) : 0.f);
        #pragma unroll
        for (int off = 32; off > 0; off >>= 1) {
            eA += __shfl_xor(eA, off);
            eB += __shfl_xor(eB, off);
        }

        emitRow(VA, baseA, kfA, c0A, totA, eA, fastA);
        emitRow(VB, baseB, kfB, c0B, totB, eB, fastB);
    };

    processPair(V[0], V[1], (row0 + 0) * ROW_N, (row0 + 1) * ROW_N);
    processPair(V[2], V[3], (row0 + 2) * ROW_N, (row0 + 3) * ROW_N);
}

extern "C" void kernel_launch(void* const* d_in, const int* in_sizes, int n_in,
                              void* d_out, int out_size, void* d_ws, size_t ws_size,
                              hipStream_t stream) {
    const float* logits = (const float*)d_in[0];
    float* out = (float*)d_out;
    const int rows = out_size / ROW_N;          // 2*8*2048 = 32768
    topk_softmax_kernel<<<dim3(rows / 16), dim3(256), 0, stream>>>(logits, out);
}

// Round 11
// 460.687 us; speedup vs baseline: 1.2530x; 1.2530x over previous
//
#include <hip/hip_runtime.h>
#include <math.h>

#define ROW_N 2048
#define KSEL 10
#define WCAP 64   // fallback candidate cap
#define RPW  8    // rows per wave (persistent, rolling prefetch)

typedef float f32x4 __attribute__((ext_vector_type(4)));
typedef unsigned long long u64;

__device__ __forceinline__ uint32_t ordbits(float x) {
    uint32_t u = __float_as_uint(x);
    return u ^ ((uint32_t)((int32_t)u >> 31) | 0x80000000u);
}
__device__ __forceinline__ float unord(uint32_t o) {
    return __uint_as_float(o ^ ((o & 0x80000000u) ? 0x80000000u : 0xFFFFFFFFu));
}

// Persistent waves + rolling prefetch. r2-r10 model: every structure that
// bursts 8 loads then goes load-silent for the whole compute phase reads
// HBM at ~0.8 TB/s (Little's law: ~KBs outstanding per CU on average),
// regardless of occupancy 18%-74%. Copy ubench (3+ TB/s read) and r5's
// spill storm (4.65 TB/s) prove the chip delivers when loads issue
// CONTINUOUSLY. Fix: 4096 waves (all resident, one generation), each owns
// 8 consecutive rows, ping-pong A/B register buffers; row i+1's 8 loads
// are issued BEFORE row i's compute, separated by an asm "memory" fence
// (scheduling order only -- NO data read, so no forced waitcnt; r10's
// "+v"-pin-per-load forced serial full-latency loads, 292us).
//
// Per row (r8/r9 math, proven exact twice): one sweep -> per-lane top-3 +
// unshifted mass 2^(xK); 10th-largest VALUE bits via 16x 2-bit ballot
// search over the {m1,m2} pool; fast path valid iff cnt(pool>=kov)==10
// and no lane's m3 >= kf (winner set value-determined); else exact
// u64-key fallback (ov<<16 | 2047-idx) preserving lax.top_k tie-break.
// Output e*(sel?0.9/ssum:0.1/rem), nontemporal, no patch pass.
__global__ __launch_bounds__(256) void topk_softmax_kernel(
    const float* __restrict__ in, float* __restrict__ out)
{
    const int lane = threadIdx.x & 63;
    const int wave = threadIdx.x >> 6;
    const size_t row0 = ((size_t)blockIdx.x * 4 + wave) * RPW;

    __shared__ u64 s_cand[4][WCAP];   // fallback only, wave-private

    const float K = 1.4426950408889634f;
    const int low0 = 2047 - lane * 4;

    f32x4 A[8], B[8];

    auto loadrow = [&](f32x4 (&V)[8], size_t row) {
        const f32x4* p = reinterpret_cast<const f32x4*>(in + row * ROW_N);
        #pragma unroll
        for (int j = 0; j < 8; ++j) V[j] = p[j * 64 + lane];
    };

    auto process = [&](f32x4 (&V)[8], size_t row) {
        // sweep: per-lane top-3 + unshifted exp2 mass (x bounded ~6: no ovf)
        float m1 = -INFINITY, m2 = -INFINITY, m3 = -INFINITY, t0 = 0.f;
        #pragma unroll
        for (int j = 0; j < 8; ++j)
            #pragma unroll
            for (int c = 0; c < 4; ++c) {
                float x = V[j][c];
                m3 = fmaxf(fminf(x, m2), m3);
                m2 = fmaxf(fminf(x, m1), m2);
                m1 = fmaxf(x, m1);
                t0 += exp2f(x * K);
            }

        float vm = m1;
        #pragma unroll
        for (int off = 32; off > 0; off >>= 1) {
            vm = fmaxf(vm, __shfl_xor(vm, off));
            t0 += __shfl_xor(t0, off);
        }

        const uint32_t o1 = ordbits(m1), o2 = ordbits(m2);
        auto cnt = [&](uint32_t t) {
            return __popcll(__ballot(o1 >= t)) + __popcll(__ballot(o2 >= t));
        };

        // 2 bits/step: 3 independent trials share one ballot round-trip
        uint32_t kov = 0;
        #pragma unroll
        for (int b = 30; b >= 0; b -= 2) {
            uint32_t t3 = kov | (3u << b), t2 = kov | (2u << b), t1 = kov | (1u << b);
            int c3 = cnt(t3), c2 = cnt(t2), c1 = cnt(t1);
            kov = (c3 >= KSEL) ? t3 : (c2 >= KSEL) ? t2 : (c1 >= KSEL) ? t1 : kov;
        }
        const float kf = unord(kov);

        const bool fast = (cnt(kov) == KSEL) && (__ballot(m3 >= kf) == 0ULL);
        const float c0v = -vm * K;
        const float tot = t0 * exp2f(c0v);

        f32x4* o4 = reinterpret_cast<f32x4*>(out + row * ROW_N);

        if (fast) {
            float ee = ((m1 >= kf) ? exp2f(fmaf(m1, K, c0v)) : 0.f) +
                       ((m2 >= kf) ? exp2f(fmaf(m2, K, c0v)) : 0.f);
            #pragma unroll
            for (int off = 32; off > 0; off >>= 1) ee += __shfl_xor(ee, off);
            const float aa = 0.9f / ee;
            const float bb = 0.1f / (tot - ee);
            #pragma unroll
            for (int j = 0; j < 8; ++j) {
                f32x4 o;
                #pragma unroll
                for (int c = 0; c < 4; ++c) {
                    float x = V[j][c];
                    o[c] = exp2f(fmaf(x, K, c0v)) * ((x >= kf) ? aa : bb);
                }
                __builtin_nontemporal_store(o, o4 + j * 64 + lane);
            }
        } else {
            // exact fallback (~3% of rows): keys ov<<16|(2047-idx)
            int C = 0;
            #pragma unroll
            for (int j = 0; j < 8; ++j)
                #pragma unroll
                for (int c = 0; c < 4; ++c) {
                    bool cond = V[j][c] >= kf;
                    u64 m = __ballot(cond);
                    if (cond) {
                        int pos = C + (int)__builtin_amdgcn_mbcnt_hi(
                                          (unsigned)(m >> 32),
                                          __builtin_amdgcn_mbcnt_lo((unsigned)m, 0u));
                        if (pos < WCAP)
                            s_cand[wave][pos] = ((u64)ordbits(V[j][c]) << 16) |
                                                (unsigned)(low0 - (j * 256 + c));
                    }
                    C += __popcll(m);
                }
            if (C > WCAP) C = WCAP;
            u64 k0 = (lane < C) ? s_cand[wave][lane] : 0ULL;
            u64 kmin = 0ULL;
            #pragma unroll 1
            for (int b = 47; b >= 0; --b) {
                u64 trial = kmin | (1ULL << b);
                if (__popcll(__ballot(k0 >= trial)) >= KSEL) kmin = trial;
            }
            uint32_t ovk = (uint32_t)(k0 >> 16);
            float val = unord(ovk);
            bool win  = (k0 >= kmin) && (k0 != 0ULL);
            float ee  = win ? exp2f(fmaf(val, K, c0v)) : 0.f;
            float ss = ee;
            #pragma unroll
            for (int off = 32; off > 0; off >>= 1) ss += __shfl_xor(ss, off);
            const float aa = 0.9f / ss;
            const float bb = 0.1f / (tot - ss);
            #pragma unroll
            for (int j = 0; j < 8; ++j) {
                f32x4 o;
                #pragma unroll
                for (int c = 0; c < 4; ++c) {
                    float x = V[j][c];
                    u64 key = ((u64)ordbits(x) << 16) |
                              (unsigned)(low0 - (j * 256 + c));
                    o[c] = exp2f(fmaf(x, K, c0v)) * ((key >= kmin) ? aa : bb);
                }
                __builtin_nontemporal_store(o, o4 + j * 64 + lane);
            }
        }
    };

    // rolling ping-pong: next row's loads are in flight under this row's
    // compute+stores. Fence = compile-time ordering only (no waitcnt).
    loadrow(A, row0);
    #pragma unroll 1
    for (int i = 0; i < RPW; i += 2) {
        loadrow(B, row0 + i + 1);
        asm volatile("" ::: "memory");
        process(A, row0 + i);
        if (i + 2 < RPW) loadrow(A, row0 + i + 2);
        asm volatile("" ::: "memory");
        process(B, row0 + i + 1);
    }
}

extern "C" void kernel_launch(void* const* d_in, const int* in_sizes, int n_in,
                              void* d_out, int out_size, void* d_ws, size_t ws_size,
                              hipStream_t stream) {
    const float* logits = (const float*)d_in[0];
    float* out = (float*)d_out;
    const int rows = out_size / ROW_N;            // 2*8*2048 = 32768
    const int waves = rows / RPW;                 // 4096 waves, all resident
    topk_softmax_kernel<<<dim3(waves / 4), dim3(256), 0, stream>>>(logits, out);
}

// Round 12
// 454.059 us; speedup vs baseline: 1.2713x; 1.0146x over previous
//
#include <hip/hip_runtime.h>
#include <math.h>

#define ROW_N 2048
#define KSEL 10
#define WCAP 64   // fallback candidate cap
#define RPW  4    // rows per wave

typedef float f32x4 __attribute__((ext_vector_type(4)));
typedef unsigned long long u64;

__device__ __forceinline__ uint32_t ordbits(float x) {
    uint32_t u = __float_as_uint(x);
    return u ^ ((uint32_t)((int32_t)u >> 31) | 0x80000000u);
}
__device__ __forceinline__ float unord(uint32_t o) {
    return __uint_as_float(o ^ ((o & 0x80000000u) ? 0x80000000u : 0xFFFFFFFFu));
}

// PHASE-STAGGERED waves. r2-r11 model: VALU-busy (51us) + HBM floor (64us)
// + DS/trans (~30us) SUMS to the observed ~165us -- the CU runs its phases
// serially because all resident waves are phase-ALIGNED (same dispatch
// instant, uniform ~4K-cycle row period): when everyone computes, memory
// idles, and vice versa. Fix under test: desynchronize by sleeping each
// wave (per-CU slot)x~140 cycles before its first load, spreading the
// ~20 co-resident waves across one row period. Slot = ((bid>>8)&7)*4+wave
// (blocks b, b+256, ... co-reside under round-robin dispatch).
// Also fixes r11's occupancy collapse: RPW=4, grid=2048 (8 blocks/CU ->
// refill slack; r11's 1024-block persistent grid decayed to 18.6% occ).
//
// Per row (r8-r11 math, proven exact): ping-pong A/B load overlap; one
// sweep -> per-lane top-3 + unshifted mass 2^(xK); 10th-largest VALUE bits
// via 16x 2-bit ballot search over the {m1,m2} pool; fast path valid iff
// cnt(pool>=kov)==10 and no lane's m3>=kf; else exact u64-key fallback
// (ov<<16 | 2047-idx) preserving lax.top_k tie-break. Output
// e*(sel?0.9/ssum:0.1/rem), nontemporal, no patch pass.
__global__ __launch_bounds__(256) void topk_softmax_kernel(
    const float* __restrict__ in, float* __restrict__ out)
{
    const int lane = threadIdx.x & 63;
    const int wave = threadIdx.x >> 6;
    const size_t row0 = ((size_t)blockIdx.x * 4 + wave) * RPW;

    __shared__ u64 s_cand[4][WCAP];   // fallback only, wave-private

    const float K = 1.4426950408889634f;
    const int low0 = 2047 - lane * 4;

    // phase stagger: slot 0..31 -> 0..~4.3K cycles of s_sleep before load
    const int slot = (((blockIdx.x >> 8) & 7) << 2) | wave;
    #pragma unroll 1
    for (int i = 0; i < slot; ++i) __builtin_amdgcn_s_sleep(2);

    f32x4 A[8], B[8];

    auto loadrow = [&](f32x4 (&V)[8], size_t row) {
        const f32x4* p = reinterpret_cast<const f32x4*>(in + row * ROW_N);
        #pragma unroll
        for (int j = 0; j < 8; ++j) V[j] = p[j * 64 + lane];
    };

    auto process = [&](f32x4 (&V)[8], size_t row) {
        // sweep: per-lane top-3 + unshifted exp2 mass (x bounded ~6: no ovf)
        float m1 = -INFINITY, m2 = -INFINITY, m3 = -INFINITY, t0 = 0.f;
        #pragma unroll
        for (int j = 0; j < 8; ++j)
            #pragma unroll
            for (int c = 0; c < 4; ++c) {
                float x = V[j][c];
                m3 = fmaxf(fminf(x, m2), m3);
                m2 = fmaxf(fminf(x, m1), m2);
                m1 = fmaxf(x, m1);
                t0 += exp2f(x * K);
            }

        float vm = m1;
        #pragma unroll
        for (int off = 32; off > 0; off >>= 1) {
            vm = fmaxf(vm, __shfl_xor(vm, off));
            t0 += __shfl_xor(t0, off);
        }

        const uint32_t o1 = ordbits(m1), o2 = ordbits(m2);
        auto cnt = [&](uint32_t t) {
            return __popcll(__ballot(o1 >= t)) + __popcll(__ballot(o2 >= t));
        };

        // 2 bits/step: 3 independent trials share one ballot round-trip
        uint32_t kov = 0;
        #pragma unroll
        for (int b = 30; b >= 0; b -= 2) {
            uint32_t t3 = kov | (3u << b), t2 = kov | (2u << b), t1 = kov | (1u << b);
            int c3 = cnt(t3), c2 = cnt(t2), c1 = cnt(t1);
            kov = (c3 >= KSEL) ? t3 : (c2 >= KSEL) ? t2 : (c1 >= KSEL) ? t1 : kov;
        }
        const float kf = unord(kov);

        const bool fast = (cnt(kov) == KSEL) && (__ballot(m3 >= kf) == 0ULL);
        const float c0v = -vm * K;
        const float tot = t0 * exp2f(c0v);

        f32x4* o4 = reinterpret_cast<f32x4*>(out + row * ROW_N);

        if (fast) {
            float ee = ((m1 >= kf) ? exp2f(fmaf(m1, K, c0v)) : 0.f) +
                       ((m2 >= kf) ? exp2f(fmaf(m2, K, c0v)) : 0.f);
            #pragma unroll
            for (int off = 32; off > 0; off >>= 1) ee += __shfl_xor(ee, off);
            const float aa = 0.9f / ee;
            const float bb = 0.1f / (tot - ee);
            #pragma unroll
            for (int j = 0; j < 8; ++j) {
                f32x4 o;
                #pragma unroll
                for (int c = 0; c < 4; ++c) {
                    float x = V[j][c];
                    o[c] = exp2f(fmaf(x, K, c0v)) * ((x >= kf) ? aa : bb);
                }
                __builtin_nontemporal_store(o, o4 + j * 64 + lane);
            }
        } else {
            // exact fallback (~3% of rows): keys ov<<16|(2047-idx)
            int C = 0;
            #pragma unroll
            for (int j = 0; j < 8; ++j)
                #pragma unroll
                for (int c = 0; c < 4; ++c) {
                    bool cond = V[j][c] >= kf;
                    u64 m = __ballot(cond);
                    if (cond) {
                        int pos = C + (int)__builtin_amdgcn_mbcnt_hi(
                                          (unsigned)(m >> 32),
                                          __builtin_amdgcn_mbcnt_lo((unsigned)m, 0u));
                        if (pos < WCAP)
                            s_cand[wave][pos] = ((u64)ordbits(V[j][c]) << 16) |
                                                (unsigned)(low0 - (j * 256 + c));
                    }
                    C += __popcll(m);
                }
            if (C > WCAP) C = WCAP;
            u64 k0 = (lane < C) ? s_cand[wave][lane] : 0ULL;
            u64 kmin = 0ULL;
            #pragma unroll 1
            for (int b = 47; b >= 0; --b) {
                u64 trial = kmin | (1ULL << b);
                if (__popcll(__ballot(k0 >= trial)) >= KSEL) kmin = trial;
            }
            uint32_t ovk = (uint32_t)(k0 >> 16);
            float val = unord(ovk);
            bool win  = (k0 >= kmin) && (k0 != 0ULL);
            float ee  = win ? exp2f(fmaf(val, K, c0v)) : 0.f;
            float ss = ee;
            #pragma unroll
            for (int off = 32; off > 0; off >>= 1) ss += __shfl_xor(ss, off);
            const float aa = 0.9f / ss;
            const float bb = 0.1f / (tot - ss);
            #pragma unroll
            for (int j = 0; j < 8; ++j) {
                f32x4 o;
                #pragma unroll
                for (int c = 0; c < 4; ++c) {
                    float x = V[j][c];
                    u64 key = ((u64)ordbits(x) << 16) |
                              (unsigned)(low0 - (j * 256 + c));
                    o[c] = exp2f(fmaf(x, K, c0v)) * ((key >= kmin) ? aa : bb);
                }
                __builtin_nontemporal_store(o, o4 + j * 64 + lane);
            }
        }
    };

    // rolling ping-pong: next row's loads in flight under this row's work
    loadrow(A, row0);
    #pragma unroll 1
    for (int i = 0; i < RPW; i += 2) {
        loadrow(B, row0 + i + 1);
        asm volatile("" ::: "memory");
        process(A, row0 + i);
        if (i + 2 < RPW) loadrow(A, row0 + i + 2);
        asm volatile("" ::: "memory");
        process(B, row0 + i + 1);
    }
}

extern "C" void kernel_launch(void* const* d_in, const int* in_sizes, int n_in,
                              void* d_out, int out_size, void* d_ws, size_t ws_size,
                              hipStream_t stream) {
    const float* logits = (const float*)d_in[0];
    float* out = (float*)d_out;
    const int rows = out_size / ROW_N;            // 2*8*2048 = 32768
    const int waves = rows / RPW;                 // 8192 waves
    topk_softmax_kernel<<<dim3(waves / 4), dim3(256), 0, stream>>>(logits, out);
}